// Round 5
// baseline (606.098 us; speedup 1.0000x reference)
//
#include <hip/hip_runtime.h>
#include <math.h>

// Problem constants (from reference)
constexpr int cS  = 16;   // sequence
constexpr int cB  = 8;    // batch
constexpr int cNC = 5;    // classes
constexpr int cD  = 256;  // hidden
constexpr int cP  = 16;   // patches
constexpr int cPD = 49;   // patch dim
#define LEPS 1e-5f
#define NBLK 256

// ---- grid barrier state (module globals: zero-init, self-restoring across
// ---- launches since the kernel executes an EVEN number of barriers).
__device__ unsigned g_cnt[2];
__device__ unsigned g_sense;

__device__ __forceinline__ float frcp(float x) { return __builtin_amdgcn_rcpf(x); }
__device__ __forceinline__ float sigm(float x) { return frcp(1.0f + __expf(-x)); }
__device__ __forceinline__ float gelu_t(float x) {
  const float z = 1.5957691216057308f * (x + 0.044715f * x * x * x);
  return x * frcp(1.0f + __expf(-z));
}

template<int CTRL>
__device__ __forceinline__ float dpp_mov(float v) {
  return __int_as_float(__builtin_amdgcn_update_dpp(
      0, __float_as_int(v), CTRL, 0xF, 0xF, true));
}
__device__ __forceinline__ float row_sum16(float v) {
  v += dpp_mov<0xB1>(v);   // quad_perm [1,0,3,2]
  v += dpp_mov<0x4E>(v);   // quad_perm [2,3,0,1]
  v += dpp_mov<0x124>(v);  // row_ror:4
  v += dpp_mov<0x128>(v);  // row_ror:8
  return v;
}
__device__ __forceinline__ float wave_sum64(float v) {
  v = row_sum16(v);
  v += __shfl_xor(v, 16, 64);
  v += __shfl_xor(v, 32, 64);
  return v;
}

// 16-dot with 4-way split chains (4-deep FMA chains + tree).
__device__ __forceinline__ float dot16(const float (&w)[16],
    const float4 a, const float4 b, const float4 c, const float4 d) {
  float s0 = w[0]  * a.x; s0 += w[1]  * a.y; s0 += w[2]  * a.z; s0 += w[3]  * a.w;
  float s1 = w[4]  * b.x; s1 += w[5]  * b.y; s1 += w[6]  * b.z; s1 += w[7]  * b.w;
  float s2 = w[8]  * c.x; s2 += w[9]  * c.y; s2 += w[10] * c.z; s2 += w[11] * c.w;
  float s3 = w[12] * d.x; s3 += w[13] * d.y; s3 += w[14] * d.z; s3 += w[15] * d.w;
  return (s0 + s1) + (s2 + s3);
}

// ---- SRWM step (LDS b128 broadcast; verified R3/R4) ----
__device__ __forceinline__ float srwm_step(
    float xv, float (&wy)[16], float (&wq)[16], float (&wk)[16], float (&wbr)[16],
    float* gl, const int r) {
  gl[r] = xv;
  __builtin_amdgcn_wave_barrier();
  const float4* g4 = (const float4*)gl;
  const float4 xa = g4[0], xb = g4[1], xc = g4[2], xd = g4[3];
  const float y  = dot16(wy,  xa, xb, xc, xd);
  const float q  = dot16(wq,  xa, xb, xc, xd);
  const float k  = dot16(wk,  xa, xb, xc, xd);
  const float bt = dot16(wbr, xa, xb, xc, xd);
  const float bsig = sigm(bt);
  const float eq = __expf(q), ek = __expf(k);
  gl[16 + r] = eq;
  gl[32 + r] = ek;
  gl[48 + r] = bsig;
  __builtin_amdgcn_wave_barrier();
  const float4 qa = g4[4], qb = g4[5], qc = g4[6],  qd = g4[7];
  const float4 ka = g4[8], kb = g4[9], kc = g4[10], kd = g4[11];
  const float4 bs4 = g4[12];
  const float ay  = dot16(wy,  qa, qb, qc, qd);
  const float vqq = dot16(wq,  qa, qb, qc, qd);
  const float vkq = dot16(wk,  qa, qb, qc, qd);
  const float vbq = dot16(wbr, qa, qb, qc, qd);
  const float vyk = dot16(wy,  ka, kb, kc, kd);
  const float vqk = dot16(wq,  ka, kb, kc, kd);
  const float vkk = dot16(wk,  ka, kb, kc, kd);
  const float vbk = dot16(wbr, ka, kb, kc, kd);
  const float sq = ((qa.x + qa.y) + (qa.z + qa.w)) + ((qb.x + qb.y) + (qb.z + qb.w))
                 + ((qc.x + qc.y) + (qc.z + qc.w)) + ((qd.x + qd.y) + (qd.z + qd.w));
  const float sk = ((ka.x + ka.y) + (ka.z + ka.w)) + ((kb.x + kb.y) + (kb.z + kb.w))
                 + ((kc.x + kc.y) + (kc.z + kc.w)) + ((kd.x + kd.y) + (kd.z + kd.w));
  const float rq = frcp(sq);
  const float rk = frcp(sk);
  const float ea = __expf(ay * rq);
  const float vyq = ea * frcp(row_sum16(ea));
  const float cy = bs4.x * (vyq      - vyk * rk) * rk;
  const float cq = bs4.y * (vqq * rq - vqk * rk) * rk;
  const float ck = bs4.z * (vkq * rq - vkk * rk) * rk;
  const float cb = bs4.w * (vbq * rq - vbk * rk) * rk;
  const float ks[16] = {ka.x, ka.y, ka.z, ka.w, kb.x, kb.y, kb.z, kb.w,
                        kc.x, kc.y, kc.z, kc.w, kd.x, kd.y, kd.z, kd.w};
#pragma unroll
  for (int j = 0; j < 16; ++j) {
    wy[j] += cy * ks[j]; wq[j] += cq * ks[j]; wk[j] += ck * ks[j]; wbr[j] += cb * ks[j];
  }
  return y;
}

// ---- shared-memory union (phases are barrier-separated) ----
struct SM_M {
  float tile[16][256];
  float W1s[1024]; float W2s[1024];
  float mean_[16]; float rstd_[16];
  float red[16][17]; float red2[16][17];
};
struct SM_X { float yv[8][256]; float lnv[8][256]; float hid[8][128]; };
struct SM_O {
  float ymat[16][256]; float gwm[cNC][256];
  float GBp[4][10]; float GBs[10]; float gscr[16][64];
};
union SMem {
  float sx[784];          // embed image stage
  float gscr[8][64];      // T/C scan scratch
  SM_M m;
  SM_X x;
  float sacc[4][256];     // fln_mean
  SM_O o;
};

struct Args {
  const float* x; const int* fb; const float* inW; const float* inb;
  const float *tkWy, *tkWq, *tkWk, *tkwb, *tklng, *tklnb;
  const float *tkmg, *tkmb, *tkmW1, *tkmb1, *tkmW2, *tkmb2;
  const float *chWy, *chWq, *chWk, *chwb, *chlng, *chlnb;
  const float *chmg, *chmb, *chmW1, *chmb1, *chmW2, *chmb2;
  const float *flng, *flnb;
  const float *oWy, *oWq, *oWk, *owb, *olng, *olnb, *outW, *outb;
  float *h, *gbuf, *y2, *outp;
};

// Sense-reversing grid barrier, alternating counters (no reset race: cnt[k&1]
// is reset at barrier k, reused at k+2, and no block can be >1 barrier ahead).
#define GSYNC()                                                                \
  do {                                                                         \
    __syncthreads();                                                           \
    ++kbar;                                                                    \
    if (t == 0) {                                                              \
      __threadfence();                                                         \
      const unsigned tgt = kbar & 1u;                                          \
      const unsigned old = __hip_atomic_fetch_add(                             \
          &g_cnt[kbar & 1u], 1u, __ATOMIC_ACQ_REL, __HIP_MEMORY_SCOPE_AGENT);  \
      if (old == (unsigned)(NBLK - 1)) {                                       \
        __hip_atomic_store(&g_cnt[kbar & 1u], 0u, __ATOMIC_RELAXED,            \
                           __HIP_MEMORY_SCOPE_AGENT);                          \
        __hip_atomic_store(&g_sense, tgt, __ATOMIC_RELEASE,                    \
                           __HIP_MEMORY_SCOPE_AGENT);                          \
      } else {                                                                 \
        while (__hip_atomic_load(&g_sense, __ATOMIC_ACQUIRE,                   \
                                 __HIP_MEMORY_SCOPE_AGENT) != tgt)             \
          __builtin_amdgcn_s_sleep(16);                                        \
      }                                                                        \
    }                                                                          \
    __syncthreads();                                                           \
  } while (0)

__global__ __launch_bounds__(256, 1) void k_mega(Args a) {
  const int t = threadIdx.x;
  const int bid = blockIdx.x;
  __shared__ __align__(16) SMem sm;
  unsigned kbar = 0;

  // ================= Phase E: embed (all 256 blocks) =================
  {
    const int sb = bid >> 1, h2 = bid & 1;
    for (int i = t; i < 784; i += 256) sm.sx[i] = a.x[(size_t)sb * 784 + i];
    __syncthreads();
    const int cls = a.fb[sb];
    const int d = t;
    float acc[8];
    const float base0 = a.inb[d] + a.inW[(size_t)(cPD + cls) * cD + d];
#pragma unroll
    for (int p8 = 0; p8 < 8; ++p8) acc[p8] = base0;
    for (int p1 = 0; p1 < 7; ++p1) {
      for (int p2 = 0; p2 < 7; ++p2) {
        const float wj = a.inW[(size_t)(p1 * 7 + p2) * cD + d];
        const int jo = p1 * 28 + p2;
#pragma unroll
        for (int p8 = 0; p8 < 8; ++p8) {
          const int p = h2 * 8 + p8;
          acc[p8] += wj * sm.sx[(p >> 2) * 196 + (p & 3) * 7 + jo];
        }
      }
    }
#pragma unroll
    for (int p8 = 0; p8 < 8; ++p8)
      a.h[((size_t)sb * cP + h2 * 8 + p8) * cD + d] = acc[p8];
  }
  GSYNC();

  for (int i = 0; i < 2; ++i) {
    // ================= Phase T: token SRWM (t<128 of all blocks) =========
    {
      const float* Wy0 = a.tkWy + i * 256;
      const float* Wq0 = a.tkWq + i * 256;
      const float* Wk0 = a.tkWk + i * 256;
      const float* wb0 = a.tkwb + i * 64;
      const float* lng = a.tklng + i * 16;
      const float* lnb = a.tklnb + i * 16;
      if (t < 128) {
        const int lane = t & 63;
        const int w    = t >> 6;
        const int r    = lane & 15;
        const int li   = lane >> 4;
        const int b    = bid >> 5;
        const int d    = ((bid & 31) << 3) + (w << 2) + li;
        float* gl = sm.gscr[t >> 4];
        float wy[16], wq[16], wk[16], wbr[16];
#pragma unroll
        for (int j = 0; j < 16; ++j) {
          wy[j]  = Wy0[r * 16 + j];
          wq[j]  = Wq0[r * 16 + j];
          wk[j]  = Wk0[r * 16 + j];
          wbr[j] = wb0[(r & 3) * 16 + j];
        }
        const float gg = lng[r], bb = lnb[r];
        float xp[16];
#pragma unroll
        for (int s = 0; s < 16; ++s)
          xp[s] = a.h[((size_t)(s * cB + b) * cP + r) * cD + d];
        for (int s = 0; s < cS; ++s) {
          const float y = srwm_step(xp[s], wy, wq, wk, wbr, gl, r);
          const float s1 = row_sum16(y);
          const float s2 = row_sum16(y * y);
          const float m = s1 * 0.0625f;
          const float var = s2 * 0.0625f - m * m;
          a.h[((size_t)(s * cB + b) * cP + r) * cD + d] =
              (y - m) * rsqrtf(var + LEPS) * gg + bb;
        }
      }
    }
    GSYNC();

    // ================= Phase M: token mixer (blocks 0..127) ==============
    if (bid < 128) {
      const float* g   = a.tkmg + i * 256;
      const float* bta = a.tkmb + i * 256;
      const float* W1  = a.tkmW1 + i * 1024;
      const float* b1  = a.tkmb1 + i * 64;
      const float* W2  = a.tkmW2 + i * 1024;
      const float* b2  = a.tkmb2 + i * 16;
      const size_t base = (size_t)bid * cP * cD;
#pragma unroll
      for (int p = 0; p < 16; ++p) sm.m.tile[p][t] = a.h[base + p * 256 + t];
      sm.m.W1s[t] = W1[t]; sm.m.W1s[t + 256] = W1[t + 256];
      sm.m.W1s[t + 512] = W1[t + 512]; sm.m.W1s[t + 768] = W1[t + 768];
      sm.m.W2s[t] = W2[t]; sm.m.W2s[t + 256] = W2[t + 256];
      sm.m.W2s[t + 512] = W2[t + 512]; sm.m.W2s[t + 768] = W2[t + 768];
      __syncthreads();
      const int p = t >> 4, l = t & 15;
      float ps = 0.f, ps2 = 0.f;
#pragma unroll
      for (int k = 0; k < 16; ++k) {
        const float v = sm.m.tile[p][l + 16 * k]; ps += v; ps2 += v * v;
      }
      sm.m.red[p][l] = ps; sm.m.red2[p][l] = ps2;
      __syncthreads();
      if (t < 16) {
        float smv = 0.f, s2 = 0.f;
#pragma unroll
        for (int k = 0; k < 16; ++k) { smv += sm.m.red[t][k]; s2 += sm.m.red2[t][k]; }
        const float m = smv * (1.f / 256.f);
        sm.m.mean_[t] = m;
        sm.m.rstd_[t] = rsqrtf(s2 * (1.f / 256.f) - m * m + LEPS);
      }
      __syncthreads();
      const float gd = g[t], bd = bta[t];
      float v[16], out[16];
#pragma unroll
      for (int pp = 0; pp < 16; ++pp) {
        v[pp] = (sm.m.tile[pp][t] - sm.m.mean_[pp]) * sm.m.rstd_[pp] * gd + bd;
        out[pp] = b2[pp];
      }
      for (int e = 0; e < 64; ++e) {
        float acc = b1[e];
#pragma unroll
        for (int pp = 0; pp < 16; ++pp) acc += v[pp] * sm.m.W1s[pp * 64 + e];
        const float ge = gelu_t(acc);
#pragma unroll
        for (int pp = 0; pp < 16; ++pp) out[pp] += ge * sm.m.W2s[e * 16 + pp];
      }
#pragma unroll
      for (int pp = 0; pp < 16; ++pp)
        a.h[base + pp * 256 + t] = sm.m.tile[pp][t] + out[pp];
    }
    GSYNC();

    // ================= Phase C: channel SRWM scan (t<128 of all blocks) ==
    {
      const float* Wy0 = a.chWy + i * 4096;
      const float* Wq0 = a.chWq + i * 4096;
      const float* Wk0 = a.chWk + i * 4096;
      const float* wb0 = a.chwb + i * 1024;
      if (t < 128) {
        const int hg = bid & 1;
        const int bp = bid >> 1;
        const int hh = (hg << 3) + (t >> 4);
        const int r  = t & 15;
        const int d  = (hg << 7) + t;
        float* gl = sm.gscr[t >> 4];
        float wy[16], wq[16], wk[16], wbr[16];
#pragma unroll
        for (int j = 0; j < 16; ++j) {
          wy[j]  = Wy0[(hh * 16 + r) * 16 + j];
          wq[j]  = Wq0[(hh * 16 + r) * 16 + j];
          wk[j]  = Wk0[(hh * 16 + r) * 16 + j];
          wbr[j] = wb0[(hh * 4 + (r & 3)) * 16 + j];
        }
        float xp[16];
#pragma unroll
        for (int s = 0; s < 16; ++s)
          xp[s] = a.h[(size_t)(s * cB * cP + bp) * cD + d];
        for (int s = 0; s < cS; ++s)
          a.y2[(size_t)(s * cB * cP + bp) * cD + d] =
              srwm_step(xp[s], wy, wq, wk, wbr, gl, r);
      }
    }
    GSYNC();

    // ================= Phase X: channel LN + mixer (all blocks, 8 rows) ==
    {
      const float* lng = a.chlng + i * 256;
      const float* lnb = a.chlnb + i * 256;
      const float* mg  = a.chmg + i * 256;
      const float* mb  = a.chmb + i * 256;
      const float* W1  = a.chmW1 + i * 32768;
      const float* b1  = a.chmb1 + i * 128;
      const float* W2  = a.chmW2 + i * 32768;
      const float* b2  = a.chmb2 + i * 256;
      const int row0 = bid * 8;
      const float4* yp4 = (const float4*)(a.y2 + (size_t)row0 * cD);
      ((float4*)sm.x.yv)[t]       = yp4[t];
      ((float4*)sm.x.yv)[t + 256] = yp4[t + 256];
      __syncthreads();
      const int r32 = t >> 5, l = t & 31;
      const float4 eg0 = ((const float4*)lng)[l * 2];
      const float4 eg1 = ((const float4*)lng)[l * 2 + 1];
      const float4 eb0 = ((const float4*)lnb)[l * 2];
      const float4 eb1 = ((const float4*)lnb)[l * 2 + 1];
      const float4 mg0 = ((const float4*)mg)[l * 2];
      const float4 mg1 = ((const float4*)mg)[l * 2 + 1];
      const float4 mb0 = ((const float4*)mb)[l * 2];
      const float4 mb1 = ((const float4*)mb)[l * 2 + 1];
      const float4 y0 = ((const float4*)sm.x.yv[r32])[l * 2];
      const float4 y1 = ((const float4*)sm.x.yv[r32])[l * 2 + 1];
      float s1 = y0.x + y0.y + y0.z + y0.w + y1.x + y1.y + y1.z + y1.w;
      float s2 = y0.x * y0.x + y0.y * y0.y + y0.z * y0.z + y0.w * y0.w +
                 y1.x * y1.x + y1.y * y1.y + y1.z * y1.z + y1.w * y1.w;
#pragma unroll
      for (int o = 1; o < 32; o <<= 1) {
        s1 += __shfl_xor(s1, o, 32);
        s2 += __shfl_xor(s2, o, 32);
      }
      const float m1 = s1 * (1.f / 256.f);
      const float rst1 = rsqrtf(s2 * (1.f / 256.f) - m1 * m1 + LEPS);
      float4 a0, a1;
      a0.x = (y0.x - m1) * rst1 * eg0.x + eb0.x; a0.y = (y0.y - m1) * rst1 * eg0.y + eb0.y;
      a0.z = (y0.z - m1) * rst1 * eg0.z + eb0.z; a0.w = (y0.w - m1) * rst1 * eg0.w + eb0.w;
      a1.x = (y1.x - m1) * rst1 * eg1.x + eb1.x; a1.y = (y1.y - m1) * rst1 * eg1.y + eb1.y;
      a1.z = (y1.z - m1) * rst1 * eg1.z + eb1.z; a1.w = (y1.w - m1) * rst1 * eg1.w + eb1.w;
      float u1 = a0.x + a0.y + a0.z + a0.w + a1.x + a1.y + a1.z + a1.w;
      float u2 = a0.x * a0.x + a0.y * a0.y + a0.z * a0.z + a0.w * a0.w +
                 a1.x * a1.x + a1.y * a1.y + a1.z * a1.z + a1.w * a1.w;
#pragma unroll
      for (int o = 1; o < 32; o <<= 1) {
        u1 += __shfl_xor(u1, o, 32);
        u2 += __shfl_xor(u2, o, 32);
      }
      const float m2 = u1 * (1.f / 256.f);
      const float rst2 = rsqrtf(u2 * (1.f / 256.f) - m2 * m2 + LEPS);
      float4 L0, L1;
      L0.x = (a0.x - m2) * rst2 * mg0.x + mb0.x; L0.y = (a0.y - m2) * rst2 * mg0.y + mb0.y;
      L0.z = (a0.z - m2) * rst2 * mg0.z + mb0.z; L0.w = (a0.w - m2) * rst2 * mg0.w + mb0.w;
      L1.x = (a1.x - m2) * rst2 * mg1.x + mb1.x; L1.y = (a1.y - m2) * rst2 * mg1.y + mb1.y;
      L1.z = (a1.z - m2) * rst2 * mg1.z + mb1.z; L1.w = (a1.w - m2) * rst2 * mg1.w + mb1.w;
      ((float4*)sm.x.lnv[r32])[l * 2]     = L0;
      ((float4*)sm.x.lnv[r32])[l * 2 + 1] = L1;
      __syncthreads();
      {
        const float4* W1f = (const float4*)W1;
        float4 acc = ((const float4*)b1)[l];
        for (int j = 0; j < 256; ++j) {
          const float xj = sm.x.lnv[r32][j];
          const float4 wv = W1f[j * 32 + l];
          acc.x += xj * wv.x; acc.y += xj * wv.y; acc.z += xj * wv.z; acc.w += xj * wv.w;
        }
        float4 hv;
        hv.x = gelu_t(acc.x); hv.y = gelu_t(acc.y);
        hv.z = gelu_t(acc.z); hv.w = gelu_t(acc.w);
        ((float4*)sm.x.hid[r32])[l] = hv;
      }
      __syncthreads();
      {
        const float4* W2f = (const float4*)W2;
        float4 o0 = ((const float4*)b2)[l * 2];
        float4 o1 = ((const float4*)b2)[l * 2 + 1];
        for (int e = 0; e < 128; ++e) {
          const float xh = sm.x.hid[r32][e];
          const float4 w0 = W2f[e * 64 + l * 2];
          const float4 w1 = W2f[e * 64 + l * 2 + 1];
          o0.x += xh * w0.x; o0.y += xh * w0.y; o0.z += xh * w0.z; o0.w += xh * w0.w;
          o1.x += xh * w1.x; o1.y += xh * w1.y; o1.z += xh * w1.z; o1.w += xh * w1.w;
        }
        o0.x += a0.x; o0.y += a0.y; o0.z += a0.z; o0.w += a0.w;
        o1.x += a1.x; o1.y += a1.y; o1.z += a1.z; o1.w += a1.w;
        float4* op = (float4*)(a.h + ((size_t)row0 + r32) * cD);
        op[l * 2]     = o0;
        op[l * 2 + 1] = o1;
      }
    }
    GSYNC();
  }

  // ================= Phase F: final LN + mean (blocks 0..127) ============
  if (bid < 128) {
    const int sb = bid;
    const int lane = t & 63, w = t >> 6;
    const float4 g4 = ((const float4*)a.flng)[lane];
    const float4 b4 = ((const float4*)a.flnb)[lane];
    float a0 = 0.f, a1 = 0.f, a2 = 0.f, a3 = 0.f;
    for (int pp = 0; pp < 4; ++pp) {
      const int p = w * 4 + pp;
      const float4 v4 = ((const float4*)(a.h + ((size_t)sb * cP + p) * cD))[lane];
      const float s1 = wave_sum64(v4.x + v4.y + v4.z + v4.w);
      const float s2 = wave_sum64(v4.x * v4.x + v4.y * v4.y + v4.z * v4.z + v4.w * v4.w);
      const float m = s1 * (1.f / 256.f);
      const float rst = rsqrtf(s2 * (1.f / 256.f) - m * m + LEPS);
      a0 += (v4.x - m) * rst * g4.x + b4.x;
      a1 += (v4.y - m) * rst * g4.y + b4.y;
      a2 += (v4.z - m) * rst * g4.z + b4.z;
      a3 += (v4.w - m) * rst * g4.w + b4.w;
    }
    float4* sp = (float4*)sm.sacc[w];
    sp[lane] = make_float4(a0, a1, a2, a3);
    __syncthreads();
    a.gbuf[(size_t)sb * cD + t] =
        (sm.sacc[0][t] + sm.sacc[1][t] + sm.sacc[2][t] + sm.sacc[3][t]) * (1.f / 16.f);
  }
  GSYNC();

  // ================= Phase O: output SRWM (blocks 0..7) ==================
  if (bid < 8) {
    const int lane = t & 63;
    const int w = t >> 6;
    const int hh = t >> 4, r = t & 15;
    const int b = bid;
    float* gl = sm.o.gscr[hh];
    float wy[16], wq[16], wk[16], wbr[16];
#pragma unroll
    for (int j = 0; j < 16; ++j) {
      wy[j]  = a.oWy[(hh * 16 + r) * 16 + j];
      wq[j]  = a.oWq[(hh * 16 + r) * 16 + j];
      wk[j]  = a.oWk[(hh * 16 + r) * 16 + j];
      wbr[j] = a.owb[(hh * 4 + (r & 3)) * 16 + j];
    }
    {
      const float gg = a.olng[t], bbl = a.olnb[t];
      float pg[cNC], pbv[cNC];
#pragma unroll
      for (int c = 0; c < cNC; ++c) {
        const float wv = a.outW[(size_t)t * cNC + c];
        const float gwv = gg * wv;
        sm.o.gwm[c][t] = gwv;
        pg[c] = wave_sum64(gwv);
        pbv[c] = wave_sum64(bbl * wv);
      }
      if (lane == 0) {
#pragma unroll
        for (int c = 0; c < cNC; ++c) { sm.o.GBp[w][c] = pg[c]; sm.o.GBp[w][5 + c] = pbv[c]; }
      }
      __syncthreads();
      if (t < 10) sm.o.GBs[t] = sm.o.GBp[0][t] + sm.o.GBp[1][t] + sm.o.GBp[2][t] + sm.o.GBp[3][t];
      __syncthreads();
    }
    float xp[16];
#pragma unroll
    for (int s = 0; s < 16; ++s) xp[s] = a.gbuf[(size_t)(s * cB + b) * cD + t];
    for (int s = 0; s < cS; ++s)
      sm.o.ymat[s][t] = srwm_step(xp[s], wy, wq, wk, wbr, gl, r);
    __syncthreads();
    for (int k2 = 0; k2 < 4; ++k2) {
      const int sidx = w * 4 + k2;
      const float4 y4 = ((const float4*)sm.o.ymat[sidx])[lane];
      const float s1 = wave_sum64(y4.x + y4.y + y4.z + y4.w);
      const float s2 = wave_sum64(y4.x * y4.x + y4.y * y4.y + y4.z * y4.z + y4.w * y4.w);
      float S[cNC];
#pragma unroll
      for (int c = 0; c < cNC; ++c) {
        const float4 g4 = ((const float4*)sm.o.gwm[c])[lane];
        S[c] = wave_sum64(y4.x * g4.x + y4.y * g4.y + y4.z * g4.z + y4.w * g4.w);
      }
      if (lane == 0) {
        const float m = s1 * (1.f / 256.f);
        const float var = s2 * (1.f / 256.f) - m * m;
        const float rst = rsqrtf(var + LEPS);
#pragma unroll
        for (int c = 0; c < cNC; ++c) {
          a.outp[(size_t)(sidx * cB + b) * cNC + c] =
              a.outb[c] + rst * S[c] - rst * m * sm.o.GBs[c] + sm.o.GBs[5 + c];
        }
      }
    }
  }
}

extern "C" void kernel_launch(void* const* d_in, const int* in_sizes, int n_in,
                              void* d_out, int out_size, void* d_ws, size_t ws_size,
                              hipStream_t stream) {
  Args a;
  a.x     = (const float*)d_in[0];
  a.fb    = (const int*)d_in[1];
  a.inW   = (const float*)d_in[2];
  a.inb   = (const float*)d_in[3];
  a.tkWy  = (const float*)d_in[4];
  a.tkWq  = (const float*)d_in[5];
  a.tkWk  = (const float*)d_in[6];
  a.tkwb  = (const float*)d_in[7];
  a.tklng = (const float*)d_in[8];
  a.tklnb = (const float*)d_in[9];
  a.tkmg  = (const float*)d_in[10];
  a.tkmb  = (const float*)d_in[11];
  a.tkmW1 = (const float*)d_in[12];
  a.tkmb1 = (const float*)d_in[13];
  a.tkmW2 = (const float*)d_in[14];
  a.tkmb2 = (const float*)d_in[15];
  a.chWy  = (const float*)d_in[16];
  a.chWq  = (const float*)d_in[17];
  a.chWk  = (const float*)d_in[18];
  a.chwb  = (const float*)d_in[19];
  a.chlng = (const float*)d_in[20];
  a.chlnb = (const float*)d_in[21];
  a.chmg  = (const float*)d_in[22];
  a.chmb  = (const float*)d_in[23];
  a.chmW1 = (const float*)d_in[24];
  a.chmb1 = (const float*)d_in[25];
  a.chmW2 = (const float*)d_in[26];
  a.chmb2 = (const float*)d_in[27];
  a.flng  = (const float*)d_in[28];
  a.flnb  = (const float*)d_in[29];
  a.oWy   = (const float*)d_in[30];
  a.oWq   = (const float*)d_in[31];
  a.oWk   = (const float*)d_in[32];
  a.owb   = (const float*)d_in[33];
  a.olng  = (const float*)d_in[34];
  a.olnb  = (const float*)d_in[35];
  a.outW  = (const float*)d_in[36];
  a.outb  = (const float*)d_in[37];

  a.h    = (float*)d_ws;                               // (S,B,P,D) 2 MB
  a.gbuf = a.h + (size_t)cS * cB * cP * cD;            // (S,B,D)
  a.y2   = a.gbuf + (size_t)cS * cB * cD;              // (S,B,P,D) 2 MB scratch
  a.outp = (float*)d_out;                              // (S,B,NC)

  k_mega<<<dim3(NBLK), dim3(256), 0, stream>>>(a);
}

// Round 7
// 289.316 us; speedup vs baseline: 2.0949x; 2.0949x over previous
//
#include <hip/hip_runtime.h>
#include <math.h>

// Problem constants (from reference)
constexpr int cS  = 16;   // sequence
constexpr int cB  = 8;    // batch
constexpr int cNC = 5;    // classes
constexpr int cD  = 256;  // hidden
constexpr int cP  = 16;   // patches
constexpr int cPD = 49;   // patch dim
#define LEPS 1e-5f
// per-group scan scratch stride (floats): x[16][16] + eq[16]+ek[16]+bsig[16]
// = 304, padded to 328 (328%32==8 -> 2-way-free bank pattern, 16B aligned)
#define GSTR 328

__device__ __forceinline__ float frcp(float x) { return __builtin_amdgcn_rcpf(x); }
__device__ __forceinline__ float sigm(float x) { return frcp(1.0f + __expf(-x)); }
__device__ __forceinline__ float gelu_t(float x) {
  const float z = 1.5957691216057308f * (x + 0.044715f * x * x * x);
  return x * frcp(1.0f + __expf(-z));
}

template<int CTRL>
__device__ __forceinline__ float dpp_mov(float v) {
  return __int_as_float(__builtin_amdgcn_update_dpp(
      0, __float_as_int(v), CTRL, 0xF, 0xF, true));
}
__device__ __forceinline__ float row_sum16(float v) {
  v += dpp_mov<0xB1>(v);   // quad_perm [1,0,3,2]
  v += dpp_mov<0x4E>(v);   // quad_perm [2,3,0,1]
  v += dpp_mov<0x124>(v);  // row_ror:4
  v += dpp_mov<0x128>(v);  // row_ror:8
  return v;
}
__device__ __forceinline__ float wave_sum64(float v) {
  v = row_sum16(v);
  v += __shfl_xor(v, 16, 64);
  v += __shfl_xor(v, 32, 64);
  return v;
}

// 16-dot with 4-way split chains (4-deep FMA chains + tree).
__device__ __forceinline__ float dot16(const float (&w)[16],
    const float4 a, const float4 b, const float4 c, const float4 d) {
  float s0 = w[0]  * a.x; s0 += w[1]  * a.y; s0 += w[2]  * a.z; s0 += w[3]  * a.w;
  float s1 = w[4]  * b.x; s1 += w[5]  * b.y; s1 += w[6]  * b.z; s1 += w[7]  * b.w;
  float s2 = w[8]  * c.x; s2 += w[9]  * c.y; s2 += w[10] * c.z; s2 += w[11] * c.w;
  float s3 = w[12] * d.x; s3 += w[13] * d.y; s3 += w[14] * d.z; s3 += w[15] * d.w;
  return (s0 + s1) + (s2 + s3);
}

// ---- scan prologue: pre-broadcast all 16 x-vectors into group scratch ----
// x is scan-independent, so the per-step x write+barrier round-trip is hoisted
// out of the serial chain entirely (R6). One wave_barrier covers all writes.
__device__ __forceinline__ void srwm_prestage(
    const float (&xp)[16], float* gl, const int r) {
#pragma unroll
  for (int s = 0; s < 16; ++s) gl[s * 16 + r] = xp[s];
  __builtin_amdgcn_wave_barrier();
}

// ---- SRWM step, pre-staged x: only ONE LDS round-trip (eq/ek/bsig) on the
// ---- per-step critical path. Wave-internal DS ordering is in-order.
__device__ __forceinline__ float srwm_step(
    float (&wy)[16], float (&wq)[16], float (&wk)[16], float (&wbr)[16],
    float* gl, const int r, const int s) {
  const float4* xg = (const float4*)(gl + s * 16);
  const float4 xa = xg[0], xb = xg[1], xc = xg[2], xd = xg[3];
  const float y  = dot16(wy,  xa, xb, xc, xd);
  const float q  = dot16(wq,  xa, xb, xc, xd);
  const float k  = dot16(wk,  xa, xb, xc, xd);
  const float bt = dot16(wbr, xa, xb, xc, xd);
  const float bsig = sigm(bt);
  const float eq = __expf(q), ek = __expf(k);
  gl[256 + r] = eq;
  gl[272 + r] = ek;
  gl[288 + r] = bsig;
  __builtin_amdgcn_wave_barrier();
  const float4* g4 = (const float4*)(gl + 256);
  const float4 qa = g4[0], qb = g4[1], qc = g4[2], qd = g4[3];
  const float4 ka = g4[4], kb = g4[5], kc = g4[6], kd = g4[7];
  const float4 bs4 = g4[8];
  const float ay  = dot16(wy,  qa, qb, qc, qd);
  const float vqq = dot16(wq,  qa, qb, qc, qd);
  const float vkq = dot16(wk,  qa, qb, qc, qd);
  const float vbq = dot16(wbr, qa, qb, qc, qd);
  const float vyk = dot16(wy,  ka, kb, kc, kd);
  const float vqk = dot16(wq,  ka, kb, kc, kd);
  const float vkk = dot16(wk,  ka, kb, kc, kd);
  const float vbk = dot16(wbr, ka, kb, kc, kd);
  const float sq = ((qa.x + qa.y) + (qa.z + qa.w)) + ((qb.x + qb.y) + (qb.z + qb.w))
                 + ((qc.x + qc.y) + (qc.z + qc.w)) + ((qd.x + qd.y) + (qd.z + qd.w));
  const float sk = ((ka.x + ka.y) + (ka.z + ka.w)) + ((kb.x + kb.y) + (kb.z + kb.w))
                 + ((kc.x + kc.y) + (kc.z + kc.w)) + ((kd.x + kd.y) + (kd.z + kd.w));
  const float rq = frcp(sq);
  const float rk = frcp(sk);
  const float ea = __expf(ay * rq);
  const float vyq = ea * frcp(row_sum16(ea));
  const float cy = bs4.x * (vyq      - vyk * rk) * rk;
  const float cq = bs4.y * (vqq * rq - vqk * rk) * rk;
  const float ck = bs4.z * (vkq * rq - vkk * rk) * rk;
  const float cb = bs4.w * (vbq * rq - vbk * rk) * rk;
  const float ks[16] = {ka.x, ka.y, ka.z, ka.w, kb.x, kb.y, kb.z, kb.w,
                        kc.x, kc.y, kc.z, kc.w, kd.x, kd.y, kd.z, kd.w};
#pragma unroll
  for (int j = 0; j < 16; ++j) {
    wy[j] += cy * ks[j]; wq[j] += cq * ks[j]; wk[j] += ck * ks[j]; wbr[j] += cb * ks[j];
  }
  return y;
}

// ---------------- embed: patchify + one-hot concat + linear ----------------
__global__ __launch_bounds__(256) void k_embed(const float* __restrict__ x,
                                               const int* __restrict__ fb,
                                               const float* __restrict__ inW,
                                               const float* __restrict__ inb,
                                               float* __restrict__ h) {
  const int blk = blockIdx.x;
  const int p  = blk & 15;
  const int sb = blk >> 4;
  const int ph = p >> 2, pw = p & 3;
  __shared__ float sx[cPD];
  const int t = threadIdx.x;
  if (t < cPD) {
    const int p1 = t / 7, p2 = t % 7;
    sx[t] = x[(size_t)sb * 784 + (ph * 7 + p1) * 28 + (pw * 7 + p2)];
  }
  __syncthreads();
  const int cls = fb[sb];
  float acc = inb[t] + inW[(size_t)(cPD + cls) * cD + t];
#pragma unroll
  for (int j = 0; j < cPD; ++j) acc += sx[j] * inW[(size_t)j * cD + t];
  h[((size_t)sb * cP + p) * cD + t] = acc;
}

// --------- token SRWM: 256 blocks x 128 threads (all 256 CUs) --------------
__global__ __launch_bounds__(128) void k_tok_srwm(
    float* __restrict__ h, const float* __restrict__ Wy0, const float* __restrict__ Wq0,
    const float* __restrict__ Wk0, const float* __restrict__ wb0,
    const float* __restrict__ lng, const float* __restrict__ lnb) {
  const int t    = threadIdx.x;
  const int lane = t & 63;
  const int w    = t >> 6;              // 0..1
  const int r    = lane & 15;
  const int li   = lane >> 4;
  const int b    = blockIdx.x >> 5;     // 8 b x 32 dgroups
  const int d    = ((blockIdx.x & 31) << 3) + (w << 2) + li;
  __shared__ __align__(16) float gscr[8][GSTR];
  float* gl = gscr[t >> 4];
  float wy[16], wq[16], wk[16], wbr[16];
#pragma unroll
  for (int j = 0; j < 16; ++j) {
    wy[j]  = Wy0[r * 16 + j];
    wq[j]  = Wq0[r * 16 + j];
    wk[j]  = Wk0[r * 16 + j];
    wbr[j] = wb0[(r & 3) * 16 + j];
  }
  const float gg = lng[r], bb = lnb[r];
  float xp[16];
#pragma unroll
  for (int s = 0; s < 16; ++s)
    xp[s] = h[((size_t)(s * cB + b) * cP + r) * cD + d];
  srwm_prestage(xp, gl, r);
  for (int s = 0; s < cS; ++s) {
    const float y = srwm_step(wy, wq, wk, wbr, gl, r, s);
    const float s1 = row_sum16(y);
    const float s2 = row_sum16(y * y);
    const float m = s1 * 0.0625f;
    const float var = s2 * 0.0625f - m * m;
    h[((size_t)(s * cB + b) * cP + r) * cD + d] = (y - m) * rsqrtf(var + LEPS) * gg + bb;
  }
}

// ---------------- token mixer: LN(D) then FFN over patch axis --------------
__global__ __launch_bounds__(256) void k_tok_mixer(
    float* __restrict__ h, const float* __restrict__ g, const float* __restrict__ bta,
    const float* __restrict__ W1, const float* __restrict__ b1,
    const float* __restrict__ W2, const float* __restrict__ b2) {
  const int sb = blockIdx.x;
  const int t = threadIdx.x;
  __shared__ float tile[16][256];
  __shared__ float W1s[16 * 64], W2s[64 * 16];
  __shared__ float mean_[16], rstd_[16];
  __shared__ float red[16][17], red2[16][17];
  const size_t base = (size_t)sb * cP * cD;
#pragma unroll
  for (int p = 0; p < 16; ++p) tile[p][t] = h[base + p * 256 + t];
  W1s[t] = W1[t]; W1s[t + 256] = W1[t + 256]; W1s[t + 512] = W1[t + 512]; W1s[t + 768] = W1[t + 768];
  W2s[t] = W2[t]; W2s[t + 256] = W2[t + 256]; W2s[t + 512] = W2[t + 512]; W2s[t + 768] = W2[t + 768];
  __syncthreads();
  const int p = t >> 4, l = t & 15;
  float ps = 0.f, ps2 = 0.f;
#pragma unroll
  for (int k = 0; k < 16; ++k) { const float v = tile[p][l + 16 * k]; ps += v; ps2 += v * v; }
  red[p][l] = ps; red2[p][l] = ps2;
  __syncthreads();
  if (t < 16) {
    float sm = 0.f, s2 = 0.f;
#pragma unroll
    for (int k = 0; k < 16; ++k) { sm += red[t][k]; s2 += red2[t][k]; }
    const float m = sm * (1.f / 256.f);
    mean_[t] = m;
    rstd_[t] = rsqrtf(s2 * (1.f / 256.f) - m * m + LEPS);
  }
  __syncthreads();
  const float gd = g[t], bd = bta[t];
  float v[16], out[16];
#pragma unroll
  for (int pp = 0; pp < 16; ++pp) {
    v[pp] = (tile[pp][t] - mean_[pp]) * rstd_[pp] * gd + bd;
    out[pp] = b2[pp];
  }
  for (int e = 0; e < 64; ++e) {
    float acc = b1[e];
#pragma unroll
    for (int pp = 0; pp < 16; ++pp) acc += v[pp] * W1s[pp * 64 + e];
    const float ge = gelu_t(acc);
#pragma unroll
    for (int pp = 0; pp < 16; ++pp) out[pp] += ge * W2s[e * 16 + pp];
  }
#pragma unroll
  for (int pp = 0; pp < 16; ++pp) h[base + pp * 256 + t] = tile[pp][t] + out[pp];
}

// --------- channel SRWM scan: 256 blocks x 128 threads (8 heads each) ------
__global__ __launch_bounds__(128) void k_ch_scan(
    const float* __restrict__ h, float* __restrict__ y2,
    const float* __restrict__ Wy0, const float* __restrict__ Wq0,
    const float* __restrict__ Wk0, const float* __restrict__ wb0) {
  const int t  = threadIdx.x;
  const int hg = blockIdx.x & 1;        // head group (0: heads 0-7, 1: 8-15)
  const int bp = blockIdx.x >> 1;       // (b,p) instance
  const int hh = (hg << 3) + (t >> 4);  // global head
  const int r  = t & 15;
  const int d  = (hg << 7) + t;         // = hh*16 + r
  __shared__ __align__(16) float gscr[8][GSTR];
  float* gl = gscr[t >> 4];
  float wy[16], wq[16], wk[16], wbr[16];
#pragma unroll
  for (int j = 0; j < 16; ++j) {
    wy[j]  = Wy0[(hh * 16 + r) * 16 + j];
    wq[j]  = Wq0[(hh * 16 + r) * 16 + j];
    wk[j]  = Wk0[(hh * 16 + r) * 16 + j];
    wbr[j] = wb0[(hh * 4 + (r & 3)) * 16 + j];
  }
  float xp[16];
#pragma unroll
  for (int s = 0; s < 16; ++s)
    xp[s] = h[(size_t)(s * cB * cP + bp) * cD + d];
  srwm_prestage(xp, gl, r);
  for (int s = 0; s < cS; ++s)
    y2[(size_t)(s * cB * cP + bp) * cD + d] = srwm_step(wy, wq, wk, wbr, gl, r, s);
}

// --------- channel LN1 + mixer: 256 blocks x 512 threads, 8 rows each ------
__global__ __launch_bounds__(512) void k_ch_ln_mix(
    const float* __restrict__ y2, float* __restrict__ h,
    const float* __restrict__ lng, const float* __restrict__ lnb,
    const float* __restrict__ mg, const float* __restrict__ mb,
    const float* __restrict__ W1, const float* __restrict__ b1,
    const float* __restrict__ W2, const float* __restrict__ b2) {
  const int u = threadIdx.x;
  const int t = u & 255;
  const int jh = u >> 8;                // 0/1: which half of the k-loop
  const int row0 = blockIdx.x * 8;
  __shared__ float yv[8][256];          // rows; reused as W2-partial buffer
  __shared__ float lnv[8][256];
  __shared__ float hid[8][128];
  __shared__ float part1[8][128];
  // cooperative load of 8 consecutive rows (2048 consecutive floats)
  const float4* yp4 = (const float4*)(y2 + (size_t)row0 * cD);
  ((float4*)yv)[u] = yp4[u];
  __syncthreads();
  const int r32 = t >> 5, l = t & 31;
  float4 a0, a1;   // SRWM-LN output (mixer residual input), jh==0 only
  if (jh == 0) {
    const float4 eg0 = ((const float4*)lng)[l * 2];
    const float4 eg1 = ((const float4*)lng)[l * 2 + 1];
    const float4 eb0 = ((const float4*)lnb)[l * 2];
    const float4 eb1 = ((const float4*)lnb)[l * 2 + 1];
    const float4 mg0 = ((const float4*)mg)[l * 2];
    const float4 mg1 = ((const float4*)mg)[l * 2 + 1];
    const float4 mb0 = ((const float4*)mb)[l * 2];
    const float4 mb1 = ((const float4*)mb)[l * 2 + 1];
    const float4 y0 = ((const float4*)yv[r32])[l * 2];
    const float4 y1 = ((const float4*)yv[r32])[l * 2 + 1];
    float s1 = y0.x + y0.y + y0.z + y0.w + y1.x + y1.y + y1.z + y1.w;
    float s2 = y0.x * y0.x + y0.y * y0.y + y0.z * y0.z + y0.w * y0.w +
               y1.x * y1.x + y1.y * y1.y + y1.z * y1.z + y1.w * y1.w;
#pragma unroll
    for (int o = 1; o < 32; o <<= 1) {
      s1 += __shfl_xor(s1, o, 32);
      s2 += __shfl_xor(s2, o, 32);
    }
    const float m1 = s1 * (1.f / 256.f);
    const float rst1 = rsqrtf(s2 * (1.f / 256.f) - m1 * m1 + LEPS);
    a0.x = (y0.x - m1) * rst1 * eg0.x + eb0.x; a0.y = (y0.y - m1) * rst1 * eg0.y + eb0.y;
    a0.z = (y0.z - m1) * rst1 * eg0.z + eb0.z; a0.w = (y0.w - m1) * rst1 * eg0.w + eb0.w;
    a1.x = (y1.x - m1) * rst1 * eg1.x + eb1.x; a1.y = (y1.y - m1) * rst1 * eg1.y + eb1.y;
    a1.z = (y1.z - m1) * rst1 * eg1.z + eb1.z; a1.w = (y1.w - m1) * rst1 * eg1.w + eb1.w;
    float u1 = a0.x + a0.y + a0.z + a0.w + a1.x + a1.y + a1.z + a1.w;
    float u2 = a0.x * a0.x + a0.y * a0.y + a0.z * a0.z + a0.w * a0.w +
               a1.x * a1.x + a1.y * a1.y + a1.z * a1.z + a1.w * a1.w;
#pragma unroll
    for (int o = 1; o < 32; o <<= 1) {
      u1 += __shfl_xor(u1, o, 32);
      u2 += __shfl_xor(u2, o, 32);
    }
    const float m2 = u1 * (1.f / 256.f);
    const float rst2 = rsqrtf(u2 * (1.f / 256.f) - m2 * m2 + LEPS);
    float4 L0, L1;
    L0.x = (a0.x - m2) * rst2 * mg0.x + mb0.x; L0.y = (a0.y - m2) * rst2 * mg0.y + mb0.y;
    L0.z = (a0.z - m2) * rst2 * mg0.z + mb0.z; L0.w = (a0.w - m2) * rst2 * mg0.w + mb0.w;
    L1.x = (a1.x - m2) * rst2 * mg1.x + mb1.x; L1.y = (a1.y - m2) * rst2 * mg1.y + mb1.y;
    L1.z = (a1.z - m2) * rst2 * mg1.z + mb1.z; L1.w = (a1.w - m2) * rst2 * mg1.w + mb1.w;
    ((float4*)lnv[r32])[l * 2]     = L0;
    ((float4*)lnv[r32])[l * 2 + 1] = L1;
  }
  __syncthreads();
  // ---- W1 GEMV: hid = gelu(lnv @ W1 + b1), j-loop split across halves ----
  {
    const float4* W1f = (const float4*)W1;
    float4 acc;
    if (jh == 0) acc = ((const float4*)b1)[l];
    else         acc = make_float4(0.f, 0.f, 0.f, 0.f);
    const float4* xrow = (const float4*)lnv[r32];
    for (int j4 = jh * 32; j4 < jh * 32 + 32; ++j4) {
      const float4 xv = xrow[j4];
      const int j = j4 * 4;
      const float4 w0 = W1f[(j + 0) * 32 + l];
      const float4 w1 = W1f[(j + 1) * 32 + l];
      const float4 w2 = W1f[(j + 2) * 32 + l];
      const float4 w3 = W1f[(j + 3) * 32 + l];
      acc.x += xv.x * w0.x + xv.y * w1.x + xv.z * w2.x + xv.w * w3.x;
      acc.y += xv.x * w0.y + xv.y * w1.y + xv.z * w2.y + xv.w * w3.y;
      acc.z += xv.x * w0.z + xv.y * w1.z + xv.z * w2.z + xv.w * w3.z;
      acc.w += xv.x * w0.w + xv.y * w1.w + xv.z * w2.w + xv.w * w3.w;
    }
    if (jh == 1) ((float4*)part1[r32])[l] = acc;
    __syncthreads();
    if (jh == 0) {
      const float4 p = ((const float4*)part1[r32])[l];
      float4 hv;
      hv.x = gelu_t(acc.x + p.x); hv.y = gelu_t(acc.y + p.y);
      hv.z = gelu_t(acc.z + p.z); hv.w = gelu_t(acc.w + p.w);
      ((float4*)hid[r32])[l] = hv;
    }
    __syncthreads();
  }
  // ---- W2 GEMV: out = hid @ W2 + b2 (+residual), e-loop split ----
  {
    const float4* W2f = (const float4*)W2;
    float4 o0, o1;
    if (jh == 0) { o0 = ((const float4*)b2)[l * 2]; o1 = ((const float4*)b2)[l * 2 + 1]; }
    else         { o0 = make_float4(0.f, 0.f, 0.f, 0.f); o1 = o0; }
    const float4* hrow = (const float4*)hid[r32];
    for (int e4 = jh * 16; e4 < jh * 16 + 16; ++e4) {
      const float4 xh = hrow[e4];
      const int e = e4 * 4;
#pragma unroll
      for (int ee = 0; ee < 4; ++ee) {
        const float xv = (ee == 0) ? xh.x : (ee == 1) ? xh.y : (ee == 2) ? xh.z : xh.w;
        const float4 w0 = W2f[(e + ee) * 64 + l * 2];
        const float4 w1 = W2f[(e + ee) * 64 + l * 2 + 1];
        o0.x += xv * w0.x; o0.y += xv * w0.y; o0.z += xv * w0.z; o0.w += xv * w0.w;
        o1.x += xv * w1.x; o1.y += xv * w1.y; o1.z += xv * w1.z; o1.w += xv * w1.w;
      }
    }
    if (jh == 1) {
      ((float4*)yv[r32])[l * 2]     = o0;   // yv dead: reuse as partial buf
      ((float4*)yv[r32])[l * 2 + 1] = o1;
    }
    __syncthreads();
    if (jh == 0) {
      const float4 p0 = ((const float4*)yv[r32])[l * 2];
      const float4 p1 = ((const float4*)yv[r32])[l * 2 + 1];
      o0.x += p0.x + a0.x; o0.y += p0.y + a0.y; o0.z += p0.z + a0.z; o0.w += p0.w + a0.w;
      o1.x += p1.x + a1.x; o1.y += p1.y + a1.y; o1.z += p1.z + a1.z; o1.w += p1.w + a1.w;
      float4* op = (float4*)(h + ((size_t)row0 + r32) * cD);
      op[l * 2]     = o0;
      op[l * 2 + 1] = o1;
    }
  }
}

// ---------------- final LN + mean over patches -----------------------------
__global__ __launch_bounds__(256) void k_fln_mean(
    const float* __restrict__ h, const float* __restrict__ gg, const float* __restrict__ bbv,
    float* __restrict__ o) {
  const int sb = blockIdx.x;
  const int t = threadIdx.x;
  const int lane = t & 63, w = t >> 6;
  const float4 g4 = ((const float4*)gg)[lane];
  const float4 b4 = ((const float4*)bbv)[lane];
  float a0 = 0.f, a1 = 0.f, a2 = 0.f, a3 = 0.f;
  for (int pp = 0; pp < 4; ++pp) {
    const int p = w * 4 + pp;
    const float4 v4 = ((const float4*)(h + ((size_t)sb * cP + p) * cD))[lane];
    const float s1 = wave_sum64(v4.x + v4.y + v4.z + v4.w);
    const float s2 = wave_sum64(v4.x * v4.x + v4.y * v4.y + v4.z * v4.z + v4.w * v4.w);
    const float m = s1 * (1.f / 256.f);
    const float rst = rsqrtf(s2 * (1.f / 256.f) - m * m + LEPS);
    a0 += (v4.x - m) * rst * g4.x + b4.x;
    a1 += (v4.y - m) * rst * g4.y + b4.y;
    a2 += (v4.z - m) * rst * g4.z + b4.z;
    a3 += (v4.w - m) * rst * g4.w + b4.w;
  }
  __shared__ float sacc[4][256];
  float4* sp = (float4*)sacc[w];
  sp[lane] = make_float4(a0, a1, a2, a3);
  __syncthreads();
  o[(size_t)sb * cD + t] = (sacc[0][t] + sacc[1][t] + sacc[2][t] + sacc[3][t]) * (1.f / 16.f);
}

// -------- output SRWM: barrier-free scan + batched LN/projection ----------
__global__ __launch_bounds__(256, 1) void k_out_srwm(
    const float* __restrict__ gin, float* __restrict__ outp,
    const float* __restrict__ Wy0, const float* __restrict__ Wq0,
    const float* __restrict__ Wk0, const float* __restrict__ wb0,
    const float* __restrict__ lng, const float* __restrict__ lnb,
    const float* __restrict__ outW, const float* __restrict__ outb) {
  const int t = threadIdx.x;
  const int lane = t & 63;
  const int w = t >> 6;
  const int hh = t >> 4, r = t & 15;
  const int b = blockIdx.x;
  __shared__ float ymat[16][256];
  __shared__ float gwm[cNC][256];
  __shared__ float GBp[4][10];
  __shared__ float GBs[10];
  __shared__ __align__(16) float gscr[16][GSTR];
  float* gl = gscr[hh];
  float wy[16], wq[16], wk[16], wbr[16];
#pragma unroll
  for (int j = 0; j < 16; ++j) {
    wy[j]  = Wy0[(hh * 16 + r) * 16 + j];
    wq[j]  = Wq0[(hh * 16 + r) * 16 + j];
    wk[j]  = Wk0[(hh * 16 + r) * 16 + j];
    wbr[j] = wb0[(hh * 4 + (r & 3)) * 16 + j];
  }
  {
    const float gg = lng[t], bbl = lnb[t];
    float pg[cNC], pbv[cNC];
#pragma unroll
    for (int c = 0; c < cNC; ++c) {
      const float wv = outW[(size_t)t * cNC + c];
      const float gwv = gg * wv;
      gwm[c][t] = gwv;
      pg[c] = wave_sum64(gwv);
      pbv[c] = wave_sum64(bbl * wv);
    }
    if (lane == 0) {
#pragma unroll
      for (int c = 0; c < cNC; ++c) { GBp[w][c] = pg[c]; GBp[w][5 + c] = pbv[c]; }
    }
    __syncthreads();
    if (t < 10) GBs[t] = GBp[0][t] + GBp[1][t] + GBp[2][t] + GBp[3][t];
    __syncthreads();
  }
  float xp[16];
#pragma unroll
  for (int s = 0; s < 16; ++s) xp[s] = gin[(size_t)(s * cB + b) * cD + t];
  srwm_prestage(xp, gl, r);
  for (int s = 0; s < cS; ++s)
    ymat[s][t] = srwm_step(wy, wq, wk, wbr, gl, r, s);
  __syncthreads();
  for (int k2 = 0; k2 < 4; ++k2) {
    const int sidx = w * 4 + k2;
    const float4 y4 = ((const float4*)ymat[sidx])[lane];
    const float s1 = wave_sum64(y4.x + y4.y + y4.z + y4.w);
    const float s2 = wave_sum64(y4.x * y4.x + y4.y * y4.y + y4.z * y4.z + y4.w * y4.w);
    float S[cNC];
#pragma unroll
    for (int c = 0; c < cNC; ++c) {
      const float4 g4 = ((const float4*)gwm[c])[lane];
      S[c] = wave_sum64(y4.x * g4.x + y4.y * g4.y + y4.z * g4.z + y4.w * g4.w);
    }
    if (lane == 0) {
      const float m = s1 * (1.f / 256.f);
      const float var = s2 * (1.f / 256.f) - m * m;
      const float rst = rsqrtf(var + LEPS);
#pragma unroll
      for (int c = 0; c < cNC; ++c) {
        outp[(size_t)(sidx * cB + b) * cNC + c] =
            outb[c] + rst * S[c] - rst * m * GBs[c] + GBs[5 + c];
      }
    }
  }
}

extern "C" void kernel_launch(void* const* d_in, const int* in_sizes, int n_in,
                              void* d_out, int out_size, void* d_ws, size_t ws_size,
                              hipStream_t stream) {
  const float* x     = (const float*)d_in[0];
  const int*   fb    = (const int*)d_in[1];
  const float* inW   = (const float*)d_in[2];
  const float* inb   = (const float*)d_in[3];
  const float* tkWy  = (const float*)d_in[4];
  const float* tkWq  = (const float*)d_in[5];
  const float* tkWk  = (const float*)d_in[6];
  const float* tkwb  = (const float*)d_in[7];
  const float* tklng = (const float*)d_in[8];
  const float* tklnb = (const float*)d_in[9];
  const float* tkmg  = (const float*)d_in[10];
  const float* tkmb  = (const float*)d_in[11];
  const float* tkmW1 = (const float*)d_in[12];
  const float* tkmb1 = (const float*)d_in[13];
  const float* tkmW2 = (const float*)d_in[14];
  const float* tkmb2 = (const float*)d_in[15];
  const float* chWy  = (const float*)d_in[16];
  const float* chWq  = (const float*)d_in[17];
  const float* chWk  = (const float*)d_in[18];
  const float* chwb  = (const float*)d_in[19];
  const float* chlng = (const float*)d_in[20];
  const float* chlnb = (const float*)d_in[21];
  const float* chmg  = (const float*)d_in[22];
  const float* chmb  = (const float*)d_in[23];
  const float* chmW1 = (const float*)d_in[24];
  const float* chmb1 = (const float*)d_in[25];
  const float* chmW2 = (const float*)d_in[26];
  const float* chmb2 = (const float*)d_in[27];
  const float* flng  = (const float*)d_in[28];
  const float* flnb  = (const float*)d_in[29];
  const float* oWy   = (const float*)d_in[30];
  const float* oWq   = (const float*)d_in[31];
  const float* oWk   = (const float*)d_in[32];
  const float* owb   = (const float*)d_in[33];
  const float* olng  = (const float*)d_in[34];
  const float* olnb  = (const float*)d_in[35];
  const float* outW  = (const float*)d_in[36];
  const float* outb  = (const float*)d_in[37];

  float* h    = (float*)d_ws;                               // (S,B,P,D) 2 MB
  float* gbuf = h + (size_t)cS * cB * cP * cD;              // (S,B,D)
  float* y2   = gbuf + (size_t)cS * cB * cD;                // (S,B,P,D) 2 MB scratch
  float* outp = (float*)d_out;                              // (S,B,NC)

  k_embed<<<dim3(cS * cB * cP), dim3(256), 0, stream>>>(x, fb, inW, inb, h);
  for (int i = 0; i < 2; ++i) {
    k_tok_srwm<<<dim3(256), dim3(128), 0, stream>>>(
        h, tkWy + i * 256, tkWq + i * 256, tkWk + i * 256, tkwb + i * 64,
        tklng + i * 16, tklnb + i * 16);
    k_tok_mixer<<<dim3(cS * cB), dim3(256), 0, stream>>>(
        h, tkmg + i * 256, tkmb + i * 256, tkmW1 + i * 1024, tkmb1 + i * 64,
        tkmW2 + i * 1024, tkmb2 + i * 16);
    k_ch_scan<<<dim3(cB * cP * 2), dim3(128), 0, stream>>>(
        h, y2, chWy + i * 4096, chWq + i * 4096, chWk + i * 4096, chwb + i * 1024);
    k_ch_ln_mix<<<dim3(cS * cB * cP / 8), dim3(512), 0, stream>>>(
        y2, h, chlng + i * 256, chlnb + i * 256,
        chmg + i * 256, chmb + i * 256, chmW1 + i * 32768, chmb1 + i * 128,
        chmW2 + i * 32768, chmb2 + i * 256);
  }
  k_fln_mean<<<dim3(cS * cB), dim3(256), 0, stream>>>(h, flng, flnb, gbuf);
  k_out_srwm<<<dim3(cB), dim3(256), 0, stream>>>(
      gbuf, outp, oWy, oWq, oWk, owb, olng, olnb, outW, outb);
}